// Round 8
// baseline (216.568 us; speedup 1.0000x reference)
//
#include <hip/hip_runtime.h>
#include <hip/hip_bf16.h>

#define N_NODES 50000
#define N_EDGES 800000
#define IN_DIM 128
#define HIDDEN 128
#define OUT_DIM 40
#define G_STRIDE 64                                       // padded g row (128B line)

#define SCAN_BS 1024
#define SCAN_BLOCKS ((N_NODES + SCAN_BS - 1) / SCAN_BS)   // 49

#define N_COPIES 8                                        // = src slices
#define HIST_STRIDE 50176                                 // line-aligned copy stride

#define HIST_BLOCKS 3128                                  // covers 800768 slots (guarded)
#define G1_BLOCKS ((N_NODES + 63) / 64)                   // 782
#define HG_GRID 3910                                      // 782 gemm1 (bid%5==4) + 3128 hist

struct __align__(8) Edge { int s; float w; };

typedef __attribute__((ext_vector_type(8))) short bf16x8;   // MFMA A/B frag (4 VGPR)
typedef __attribute__((ext_vector_type(4))) float f32x4;    // MFMA C/D frag
typedef __attribute__((ext_vector_type(8))) unsigned short u16x8;
typedef __attribute__((ext_vector_type(4))) unsigned short u16x4;

// fp32 -> bf16 bits with round-to-nearest-even
__device__ __forceinline__ unsigned f32_to_bf16_bits(float f) {
    unsigned u = __float_as_uint(f);
    return (u + 0x7FFFu + ((u >> 16) & 1u)) >> 16;
}
// bf16 bits -> fp32
__device__ __forceinline__ float b2f(unsigned short u) {
    return __uint_as_float(((unsigned)u) << 16);
}
// src -> slice 0..7 (6250 nodes per slice). MUST match between hist & scatter.
// Makes scan_partial's per-copy prefix order every CSR segment by src slice
// -> SpMM gathers walk y/g slice-by-slice -> 1.6MB working set fits XCD L2.
__device__ __forceinline__ int src_slice(int s) {
    return (int)((unsigned)s / 6250u);                    // compiler magic-mul
}

// ---- 1) fused hist + gemm1, INTERLEAVED 1:4. copy = src_slice(src):
// the ranked histogram doubles as a per-node counting sort by src slice.
__global__ __launch_bounds__(256) void hist_gemm1(const int* __restrict__ dst,
                                                  const int* __restrict__ srcv,
                                                  int* __restrict__ hist8,
                                                  unsigned short* __restrict__ erank,
                                                  const float* __restrict__ x,
                                                  const float* __restrict__ W1,
                                                  __hip_bfloat16* __restrict__ y)
{
    __shared__ bf16x8 w1s[2048];                  // 32 KB (gemm1 blocks only)
    int bid = blockIdx.x;

    if ((bid % 5) != 4) {
        // -------- hist path --------
        int hb = bid - bid / 5;                   // 0..3127
        int i = hb * 256 + threadIdx.x;
        if (i < N_EDGES) {
            int copy = src_slice(srcv[i]);
            erank[i] = (unsigned short)atomicAdd(&hist8[copy * HIST_STRIDE + dst[i]], 1);
        }
        return;
    }

    // -------- gemm1 path: y = x @ W1 (v_mfma_f32_16x16x32_bf16) --------
    int gb = bid / 5;                             // 0..781
    int t = threadIdx.x;
    for (int f = t; f < 2048; f += 256) {         // 8 frags per thread
        int lane = f & 63;
        int nt = (f >> 6) & 7;
        int ks = f >> 9;
        int m = lane & 15, quad = lane >> 4;
        bf16x8 frag;
        #pragma unroll
        for (int j = 0; j < 8; ++j) {
            int k = ks * 32 + quad * 8 + j;
            frag[j] = (short)f32_to_bf16_bits(W1[k * HIDDEN + nt * 16 + m]);
        }
        w1s[f] = frag;
    }
    __syncthreads();

    int wv = t >> 6;
    int lane = t & 63;
    int m = lane & 15, quad = lane >> 4;
    int row0 = gb * 64 + wv * 16;
    int arow = row0 + m;
    if (arow >= N_NODES) arow = N_NODES - 1;      // clamp loads; stores guarded

    bf16x8 afrag[4];
    #pragma unroll
    for (int ks = 0; ks < 4; ++ks) {
        const float4* xp = (const float4*)(x + (long long)arow * IN_DIM + ks * 32 + quad * 8);
        float4 a0 = xp[0], a1 = xp[1];
        afrag[ks][0] = (short)f32_to_bf16_bits(a0.x);
        afrag[ks][1] = (short)f32_to_bf16_bits(a0.y);
        afrag[ks][2] = (short)f32_to_bf16_bits(a0.z);
        afrag[ks][3] = (short)f32_to_bf16_bits(a0.w);
        afrag[ks][4] = (short)f32_to_bf16_bits(a1.x);
        afrag[ks][5] = (short)f32_to_bf16_bits(a1.y);
        afrag[ks][6] = (short)f32_to_bf16_bits(a1.z);
        afrag[ks][7] = (short)f32_to_bf16_bits(a1.w);
    }

    f32x4 acc[8];
    #pragma unroll
    for (int nt = 0; nt < 8; ++nt) acc[nt] = (f32x4){0.f, 0.f, 0.f, 0.f};

    #pragma unroll
    for (int ks = 0; ks < 4; ++ks) {
        #pragma unroll
        for (int nt = 0; nt < 8; ++nt) {
            bf16x8 bfrag = w1s[(ks * 8 + nt) * 64 + lane];
            acc[nt] = __builtin_amdgcn_mfma_f32_16x16x32_bf16(afrag[ks], bfrag, acc[nt], 0, 0, 0);
        }
    }

    #pragma unroll
    for (int nt = 0; nt < 8; ++nt) {
        #pragma unroll
        for (int r = 0; r < 4; ++r) {
            int rrow = row0 + quad * 4 + r;
            if (rrow < N_NODES)
                y[(long long)rrow * HIDDEN + nt * 16 + m] = __float2bfloat16(acc[nt][r]);
        }
    }
}

// ---- 2a) convert 8 copies -> per-copy exclusive offsets (in place) -------
__global__ __launch_bounds__(SCAN_BS) void scan_partial(int* __restrict__ hist8,
                                                        int* __restrict__ cnt,
                                                        int* __restrict__ block_sums)
{
    __shared__ int red[SCAN_BS / 64];
    int i = blockIdx.x * SCAN_BS + threadIdx.x;
    int total = 0;
    if (i < N_NODES) {
        int off = 0;
        #pragma unroll
        for (int c = 0; c < N_COPIES; ++c) {
            int h = hist8[c * HIST_STRIDE + i];
            hist8[c * HIST_STRIDE + i] = off;     // exclusive prefix over copies
            off += h;
        }
        total = off;
        cnt[i] = total;
    }
    int s = total;
    for (int off = 32; off > 0; off >>= 1) s += __shfl_down(s, off, 64);
    int wave = threadIdx.x >> 6, lane = threadIdx.x & 63;
    if (lane == 0) red[wave] = s;
    __syncthreads();
    if (threadIdx.x == 0) {
        int tt = 0;
        #pragma unroll
        for (int wv = 0; wv < SCAN_BS / 64; ++wv) tt += red[wv];
        block_sums[blockIdx.x] = tt;
    }
}

// ---- 2b) block-local exclusive scan; PARALLEL prefix over block_sums -----
__global__ __launch_bounds__(SCAN_BS) void scan_final(const int* __restrict__ cnt,
                                                      const int* __restrict__ block_sums,
                                                      int* __restrict__ row_ptr)
{
    __shared__ int tmp[SCAN_BS];
    __shared__ int blk_off;
    int t = threadIdx.x;
    int i = blockIdx.x * SCAN_BS + t;
    if (t < 64) {                                  // SCAN_BLOCKS=49 <= 64 lanes
        int v2 = (t < (int)blockIdx.x) ? block_sums[t] : 0;
        for (int off = 32; off > 0; off >>= 1) v2 += __shfl_down(v2, off, 64);
        if (t == 0) {
            blk_off = v2;
            if (blockIdx.x == 0) row_ptr[N_NODES] = N_EDGES;
        }
    }
    int v = (i < N_NODES) ? cnt[i] : 0;
    tmp[t] = v;
    __syncthreads();
    for (int off = 1; off < SCAN_BS; off <<= 1) {
        int u = (t >= off) ? tmp[t - off] : 0;
        __syncthreads();
        tmp[t] += u;
        __syncthreads();
    }
    if (i < N_NODES) row_ptr[i] = tmp[t] - v + blk_off;
}

// ---- 3) scatter_det: SINGLE-PASS deterministic placement, NO atomics.
// copy recomputed from src (same function as hist) -> placement sorted by
// src slice within each node's segment.
__global__ __launch_bounds__(256) void scatter_det(const int* __restrict__ src,
                                                   const int* __restrict__ dst,
                                                   const float* __restrict__ w,
                                                   const int* __restrict__ hist8,
                                                   const unsigned short* __restrict__ erank,
                                                   const int* __restrict__ row_ptr,
                                                   Edge* __restrict__ edges)
{
    int i = blockIdx.x * 256 + threadIdx.x;       // grid exact: 3125*256
    int d = dst[i];
    int s = src[i];
    int copy = src_slice(s);
    int pos = row_ptr[d] + hist8[copy * HIST_STRIDE + d] + (int)erank[i];
    Edge ed; ed.s = s; ed.w = w[i];
    edges[pos] = ed;
}

// ---- 4) spmm1: h1 = relu(A @ y + b1). 16-lane groups, 16B/lane; segments
// are src-slice-ordered so co-resident groups gather from the same 1.6MB
// slice of y -> XCD-L2 hits instead of IF$ round-trips ---------------------
__global__ __launch_bounds__(256) void spmm1_kernel(const int* __restrict__ row_ptr,
                                                    const Edge* __restrict__ edges,
                                                    const __hip_bfloat16* __restrict__ y,
                                                    const float* __restrict__ b1,
                                                    __hip_bfloat16* __restrict__ h1)
{
    int wv = threadIdx.x >> 6;
    int lane = threadIdx.x & 63;
    int grp = lane >> 4;                          // 0..3
    int sub = lane & 15;                          // 0..15
    int node = blockIdx.x * 16 + wv * 4 + grp;    // grid exact: 3125*16 = 50000
    int j = row_ptr[node];
    int e = row_ptr[node + 1];

    float acc[8];
    #pragma unroll
    for (int k = 0; k < 8; ++k) acc[k] = 0.f;

    for (; j + 7 < e; j += 8) {
        Edge ed[8];
        #pragma unroll
        for (int u = 0; u < 8; ++u) ed[u] = edges[j + u];
        u16x8 v[8];
        #pragma unroll
        for (int u = 0; u < 8; ++u)
            v[u] = *(const u16x8*)(y + ((long long)ed[u].s << 7) + (sub << 3));
        #pragma unroll
        for (int u = 0; u < 8; ++u) {
            #pragma unroll
            for (int k = 0; k < 8; ++k)
                acc[k] = fmaf(ed[u].w, b2f(v[u][k]), acc[k]);
        }
    }
    for (; j + 3 < e; j += 4) {
        Edge ed[4];
        #pragma unroll
        for (int u = 0; u < 4; ++u) ed[u] = edges[j + u];
        u16x8 v[4];
        #pragma unroll
        for (int u = 0; u < 4; ++u)
            v[u] = *(const u16x8*)(y + ((long long)ed[u].s << 7) + (sub << 3));
        #pragma unroll
        for (int u = 0; u < 4; ++u) {
            #pragma unroll
            for (int k = 0; k < 8; ++k)
                acc[k] = fmaf(ed[u].w, b2f(v[u][k]), acc[k]);
        }
    }
    for (; j < e; ++j) {
        Edge ed0 = edges[j];
        u16x8 v0 = *(const u16x8*)(y + ((long long)ed0.s << 7) + (sub << 3));
        #pragma unroll
        for (int k = 0; k < 8; ++k)
            acc[k] = fmaf(ed0.w, b2f(v0[k]), acc[k]);
    }

    float4 bA = *(const float4*)(b1 + (sub << 3));
    float4 bB = *(const float4*)(b1 + (sub << 3) + 4);
    u16x8 hv;
    hv[0] = (unsigned short)f32_to_bf16_bits(fmaxf(acc[0] + bA.x, 0.f));
    hv[1] = (unsigned short)f32_to_bf16_bits(fmaxf(acc[1] + bA.y, 0.f));
    hv[2] = (unsigned short)f32_to_bf16_bits(fmaxf(acc[2] + bA.z, 0.f));
    hv[3] = (unsigned short)f32_to_bf16_bits(fmaxf(acc[3] + bA.w, 0.f));
    hv[4] = (unsigned short)f32_to_bf16_bits(fmaxf(acc[4] + bB.x, 0.f));
    hv[5] = (unsigned short)f32_to_bf16_bits(fmaxf(acc[5] + bB.y, 0.f));
    hv[6] = (unsigned short)f32_to_bf16_bits(fmaxf(acc[6] + bB.z, 0.f));
    hv[7] = (unsigned short)f32_to_bf16_bits(fmaxf(acc[7] + bB.w, 0.f));
    *(u16x8*)(h1 + ((long long)node << 7) + (sub << 3)) = hv;
}

// ---- 5) gemm2: g = h1 @ W2; 8 rows/block amortize the W2 pass. Pad cols
// 40..63 with zeros so every g row is a complete 128B line -----------------
#define G2_ROWS 8
__global__ __launch_bounds__(64) void gemm2_kernel(const __hip_bfloat16* __restrict__ h1,
                                                   const float* __restrict__ W2,
                                                   __hip_bfloat16* __restrict__ g)
{
    __shared__ float xs[G2_ROWS][HIDDEN];
    int row0 = blockIdx.x * G2_ROWS;
    int t = threadIdx.x;
    #pragma unroll
    for (int r = 0; r < G2_ROWS; ++r) {
        xs[r][t]      = __bfloat162float(h1[(long long)(row0 + r) * HIDDEN + t]);
        xs[r][t + 64] = __bfloat162float(h1[(long long)(row0 + r) * HIDDEN + t + 64]);
    }
    __syncthreads();
    if (t >= OUT_DIM) {
        __hip_bfloat16 z = __float2bfloat16(0.f);
        #pragma unroll
        for (int r = 0; r < G2_ROWS; ++r)
            g[((row0 + r) << 6) + t] = z;          // zero the pad cols 40..63
        return;
    }
    float acc[G2_ROWS];
    #pragma unroll
    for (int r = 0; r < G2_ROWS; ++r) acc[r] = 0.f;
    #pragma unroll 4
    for (int k = 0; k < HIDDEN; ++k) {
        float wv = W2[k * OUT_DIM + t];
        #pragma unroll
        for (int r = 0; r < G2_ROWS; ++r)
            acc[r] = fmaf(xs[r][k], wv, acc[r]);
    }
    #pragma unroll
    for (int r = 0; r < G2_ROWS; ++r)
        g[((row0 + r) << 6) + t] = __float2bfloat16(acc[r]);   // padded row
}

// ---- 6) spmm2: out = A @ g + b2. 16-lane groups, 8B/lane = one 128B line;
// src-slice-ordered segments give g (800KB/slice) L2 residency -------------
__global__ __launch_bounds__(256) void spmm2_kernel(const int* __restrict__ row_ptr,
                                                    const Edge* __restrict__ edges,
                                                    const __hip_bfloat16* __restrict__ g,
                                                    const float* __restrict__ b2,
                                                    float* __restrict__ out)
{
    int wv = threadIdx.x >> 6;
    int lane = threadIdx.x & 63;
    int grp = lane >> 4;                          // 0..3
    int sub = lane & 15;                          // 0..15
    int node = blockIdx.x * 16 + wv * 4 + grp;    // grid exact: 3125*16 = 50000
    int j = row_ptr[node];
    int e = row_ptr[node + 1];

    float acc[4];
    #pragma unroll
    for (int k = 0; k < 4; ++k) acc[k] = 0.f;

    for (; j + 7 < e; j += 8) {
        Edge ed[8];
        #pragma unroll
        for (int u = 0; u < 8; ++u) ed[u] = edges[j + u];
        u16x4 v[8];
        #pragma unroll
        for (int u = 0; u < 8; ++u)
            v[u] = *(const u16x4*)(g + ((long long)ed[u].s << 6) + (sub << 2));
        #pragma unroll
        for (int u = 0; u < 8; ++u) {
            #pragma unroll
            for (int k = 0; k < 4; ++k)
                acc[k] = fmaf(ed[u].w, b2f(v[u][k]), acc[k]);
        }
    }
    for (; j + 3 < e; j += 4) {
        Edge ed[4];
        #pragma unroll
        for (int u = 0; u < 4; ++u) ed[u] = edges[j + u];
        u16x4 v[4];
        #pragma unroll
        for (int u = 0; u < 4; ++u)
            v[u] = *(const u16x4*)(g + ((long long)ed[u].s << 6) + (sub << 2));
        #pragma unroll
        for (int u = 0; u < 4; ++u) {
            #pragma unroll
            for (int k = 0; k < 4; ++k)
                acc[k] = fmaf(ed[u].w, b2f(v[u][k]), acc[k]);
        }
    }
    for (; j < e; ++j) {
        Edge ed0 = edges[j];
        u16x4 v0 = *(const u16x4*)(g + ((long long)ed0.s << 6) + (sub << 2));
        #pragma unroll
        for (int k = 0; k < 4; ++k)
            acc[k] = fmaf(ed0.w, b2f(v0[k]), acc[k]);
    }

    if (sub < 10) {                               // cols 4*sub..4*sub+3 < 40
        float4 bb = *(const float4*)(b2 + (sub << 2));
        float4 o;
        o.x = acc[0] + bb.x;
        o.y = acc[1] + bb.y;
        o.z = acc[2] + bb.z;
        o.w = acc[3] + bb.w;
        *(float4*)(out + (long long)node * OUT_DIM + (sub << 2)) = o;
    }
}

extern "C" void kernel_launch(void* const* d_in, const int* in_sizes, int n_in,
                              void* d_out, int out_size, void* d_ws, size_t ws_size,
                              hipStream_t stream)
{
    const float* x    = (const float*)d_in[0];
    const int*   esrc = (const int*)  d_in[1];
    const int*   edst = (const int*)  d_in[2];
    const float* ew   = (const float*)d_in[3];
    const float* W1   = (const float*)d_in[4];
    const float* b1   = (const float*)d_in[5];
    const float* W2   = (const float*)d_in[6];
    const float* b2   = (const float*)d_in[7];
    float* out = (float*)d_out;

    // workspace layout (~36 MB); g aliases y (y is dead after spmm1)
    __hip_bfloat16* y  = (__hip_bfloat16*)d_ws;                  // 12.8 MB
    __hip_bfloat16* g  = y;                                      // 6.4 MB (aliased)
    __hip_bfloat16* h1 = y + (size_t)N_NODES * HIDDEN;           // 12.8 MB
    Edge* edges     = (Edge*)(h1 + (size_t)N_NODES * HIDDEN);    // 6.4 MB
    int* hist8      = (int*)(edges + N_EDGES);                   // 1.6 MB (8 copies)
    unsigned short* erank = (unsigned short*)(hist8 + N_COPIES * HIST_STRIDE); // 1.6 MB
    int* cnt        = (int*)(erank + N_EDGES);                   // 200 KB
    int* row_ptr    = cnt + 50176;                               // 50001 (pad 50176)
    int* block_sums = row_ptr + 50176;                           // 64 ints

    // CSR build + gemm1 co-run (interleaved 1:4 so MFMA overlaps atomics)
    hipMemsetAsync(hist8, 0, N_COPIES * HIST_STRIDE * sizeof(int), stream);
    hist_gemm1<<<HG_GRID, 256, 0, stream>>>(edst, esrc, hist8, erank, x, W1, y);
    scan_partial<<<SCAN_BLOCKS, SCAN_BS, 0, stream>>>(hist8, cnt, block_sums);
    scan_final<<<SCAN_BLOCKS, SCAN_BS, 0, stream>>>(cnt, block_sums, row_ptr);
    scatter_det<<<N_EDGES / 256, 256, 0, stream>>>(esrc, edst, ew, hist8,
                                                   erank, row_ptr, edges);

    // h1 = relu(A @ y + b1)  (src-slice-ordered gathers)
    spmm1_kernel<<<N_NODES / 16, 256, 0, stream>>>(row_ptr, edges, y, b1, h1);
    // g = h1 @ W2 (8-row W2 amortization; padded+zero-filled g rows)
    gemm2_kernel<<<N_NODES / G2_ROWS, 64, 0, stream>>>(h1, W2, g);
    // out = A @ g + b2  (src-slice-ordered gathers)
    spmm2_kernel<<<N_NODES / 16, 256, 0, stream>>>(row_ptr, edges, g, b2, out);
}

// Round 9
// 202.091 us; speedup vs baseline: 1.0716x; 1.0716x over previous
//
#include <hip/hip_runtime.h>
#include <hip/hip_bf16.h>

#define N_NODES 50000
#define N_EDGES 800000
#define IN_DIM 128
#define HIDDEN 128
#define OUT_DIM 40
#define G_STRIDE 64                                       // padded g row (128B line)

#define SCAN_BS 1024
#define SCAN_BLOCKS ((N_NODES + SCAN_BS - 1) / SCAN_BS)   // 49

#define N_COPIES 8                                        // = src slices
#define HIST_STRIDE 50176                                 // line-aligned copy stride
#define FLAG_BASE 50000                                   // flags in copy-0 spare slots

#define HIST_BLOCKS 3128                                  // covers 800768 slots (guarded)
#define G1_BLOCKS ((N_NODES + 63) / 64)                   // 782
#define HG_GRID 3910                                      // 782 gemm1 (bid%5==4) + 3128 hist

struct __align__(8) Edge { int s; float w; };

typedef __attribute__((ext_vector_type(8))) short bf16x8;   // MFMA A/B frag (4 VGPR)
typedef __attribute__((ext_vector_type(4))) float f32x4;    // MFMA C/D frag
typedef __attribute__((ext_vector_type(8))) unsigned short u16x8;
typedef __attribute__((ext_vector_type(4))) unsigned short u16x4;

// fp32 -> bf16 bits with round-to-nearest-even
__device__ __forceinline__ unsigned f32_to_bf16_bits(float f) {
    unsigned u = __float_as_uint(f);
    return (u + 0x7FFFu + ((u >> 16) & 1u)) >> 16;
}
// bf16 bits -> fp32
__device__ __forceinline__ float b2f(unsigned short u) {
    return __uint_as_float(((unsigned)u) << 16);
}
// src -> slice 0..7 (6250 nodes per slice); shared by hist & scatter.
__device__ __forceinline__ int src_slice(int s) {
    return (int)((unsigned)s / 6250u);
}

// ---- 1) fused hist + gemm1, INTERLEAVED 1:4 (hist = measured ~40us
// returning-atomic floor; gemm1 MFMA hides underneath) ---------------------
__global__ __launch_bounds__(256) void hist_gemm1(const int* __restrict__ dst,
                                                  const int* __restrict__ srcv,
                                                  int* __restrict__ hist8,
                                                  unsigned short* __restrict__ erank,
                                                  const float* __restrict__ x,
                                                  const float* __restrict__ W1,
                                                  __hip_bfloat16* __restrict__ y)
{
    __shared__ bf16x8 w1s[2048];                  // 32 KB (gemm1 blocks only)
    int bid = blockIdx.x;

    if ((bid % 5) != 4) {
        // -------- hist path --------
        int hb = bid - bid / 5;                   // 0..3127
        int i = hb * 256 + threadIdx.x;
        if (i < N_EDGES) {
            int copy = src_slice(srcv[i]);
            erank[i] = (unsigned short)atomicAdd(&hist8[copy * HIST_STRIDE + dst[i]], 1);
        }
        return;
    }

    // -------- gemm1 path: y = x @ W1 (v_mfma_f32_16x16x32_bf16) --------
    int gb = bid / 5;                             // 0..781
    int t = threadIdx.x;
    for (int f = t; f < 2048; f += 256) {         // 8 frags per thread
        int lane = f & 63;
        int nt = (f >> 6) & 7;
        int ks = f >> 9;
        int m = lane & 15, quad = lane >> 4;
        bf16x8 frag;
        #pragma unroll
        for (int j = 0; j < 8; ++j) {
            int k = ks * 32 + quad * 8 + j;
            frag[j] = (short)f32_to_bf16_bits(W1[k * HIDDEN + nt * 16 + m]);
        }
        w1s[f] = frag;
    }
    __syncthreads();

    int wv = t >> 6;
    int lane = t & 63;
    int m = lane & 15, quad = lane >> 4;
    int row0 = gb * 64 + wv * 16;
    int arow = row0 + m;
    if (arow >= N_NODES) arow = N_NODES - 1;      // clamp loads; stores guarded

    bf16x8 afrag[4];
    #pragma unroll
    for (int ks = 0; ks < 4; ++ks) {
        const float4* xp = (const float4*)(x + (long long)arow * IN_DIM + ks * 32 + quad * 8);
        float4 a0 = xp[0], a1 = xp[1];
        afrag[ks][0] = (short)f32_to_bf16_bits(a0.x);
        afrag[ks][1] = (short)f32_to_bf16_bits(a0.y);
        afrag[ks][2] = (short)f32_to_bf16_bits(a0.z);
        afrag[ks][3] = (short)f32_to_bf16_bits(a0.w);
        afrag[ks][4] = (short)f32_to_bf16_bits(a1.x);
        afrag[ks][5] = (short)f32_to_bf16_bits(a1.y);
        afrag[ks][6] = (short)f32_to_bf16_bits(a1.z);
        afrag[ks][7] = (short)f32_to_bf16_bits(a1.w);
    }

    f32x4 acc[8];
    #pragma unroll
    for (int nt = 0; nt < 8; ++nt) acc[nt] = (f32x4){0.f, 0.f, 0.f, 0.f};

    #pragma unroll
    for (int ks = 0; ks < 4; ++ks) {
        #pragma unroll
        for (int nt = 0; nt < 8; ++nt) {
            bf16x8 bfrag = w1s[(ks * 8 + nt) * 64 + lane];
            acc[nt] = __builtin_amdgcn_mfma_f32_16x16x32_bf16(afrag[ks], bfrag, acc[nt], 0, 0, 0);
        }
    }

    #pragma unroll
    for (int nt = 0; nt < 8; ++nt) {
        #pragma unroll
        for (int r = 0; r < 4; ++r) {
            int rrow = row0 + quad * 4 + r;
            if (rrow < N_NODES)
                y[(long long)rrow * HIDDEN + nt * 16 + m] = __float2bfloat16(acc[nt][r]);
        }
    }
}

// ---- 2) scan_fused: per-copy offset conversion + block totals + cross-block
// prefix via release/acquire spin (49 blocks <= 2/CU -> all co-resident;
// block b spins only on blocks < b: acyclic, deadlock-free) + local scan ----
__global__ __launch_bounds__(SCAN_BS) void scan_fused(int* __restrict__ hist8,
                                                      int* __restrict__ row_ptr)
{
    __shared__ int tmp[SCAN_BS];
    __shared__ int red[SCAN_BS / 64];
    __shared__ int blk_off;
    int t = threadIdx.x;
    int bid = blockIdx.x;
    int i = bid * SCAN_BS + t;

    int total = 0;
    if (i < N_NODES) {
        int off = 0;
        #pragma unroll
        for (int c = 0; c < N_COPIES; ++c) {
            int h = hist8[c * HIST_STRIDE + i];
            hist8[c * HIST_STRIDE + i] = off;     // exclusive prefix over copies
            off += h;
        }
        total = off;
    }
    // block total
    int s = total;
    for (int off = 32; off > 0; off >>= 1) s += __shfl_down(s, off, 64);
    int wave = t >> 6, lane = t & 63;
    if (lane == 0) red[wave] = s;
    __syncthreads();
    if (t == 0) {
        int tt = 0;
        #pragma unroll
        for (int wv = 0; wv < SCAN_BS / 64; ++wv) tt += red[wv];
        __hip_atomic_store(&hist8[FLAG_BASE + bid], tt + 1,
                           __ATOMIC_RELEASE, __HIP_MEMORY_SCOPE_AGENT);
    }
    // cross-block exclusive prefix: lane t sums flagged totals of blocks < bid
    if (t < 64) {
        int v2 = 0;
        if (t < bid) {
            int v;
            do {
                v = __hip_atomic_load(&hist8[FLAG_BASE + t],
                                      __ATOMIC_ACQUIRE, __HIP_MEMORY_SCOPE_AGENT);
            } while (v == 0);
            v2 = v - 1;
        }
        for (int off = 32; off > 0; off >>= 1) v2 += __shfl_down(v2, off, 64);
        if (t == 0) {
            blk_off = v2;
            if (bid == 0) row_ptr[N_NODES] = N_EDGES;
        }
    }
    // block-local exclusive scan
    int v = total;
    tmp[t] = v;
    __syncthreads();
    for (int off = 1; off < SCAN_BS; off <<= 1) {
        int u = (t >= off) ? tmp[t - off] : 0;
        __syncthreads();
        tmp[t] += u;
        __syncthreads();
    }
    if (i < N_NODES) row_ptr[i] = tmp[t] - v + blk_off;
}

// ---- 3) scatter_det: SINGLE-PASS deterministic placement, NO atomics -----
__global__ __launch_bounds__(256) void scatter_det(const int* __restrict__ src,
                                                   const int* __restrict__ dst,
                                                   const float* __restrict__ w,
                                                   const int* __restrict__ hist8,
                                                   const unsigned short* __restrict__ erank,
                                                   const int* __restrict__ row_ptr,
                                                   Edge* __restrict__ edges)
{
    int i = blockIdx.x * 256 + threadIdx.x;       // grid exact: 3125*256
    int d = dst[i];
    int s = src[i];
    int copy = src_slice(s);
    int pos = row_ptr[d] + hist8[copy * HIST_STRIDE + d] + (int)erank[i];
    Edge ed; ed.s = s; ed.w = w[i];
    edges[pos] = ed;
}

// ---- 4) spmm1: h1 = relu(A @ y + b1). 16-lane groups, 16B/lane, 4 nodes
// per wave, 8-deep gather chains -------------------------------------------
__global__ __launch_bounds__(256) void spmm1_kernel(const int* __restrict__ row_ptr,
                                                    const Edge* __restrict__ edges,
                                                    const __hip_bfloat16* __restrict__ y,
                                                    const float* __restrict__ b1,
                                                    __hip_bfloat16* __restrict__ h1)
{
    int wv = threadIdx.x >> 6;
    int lane = threadIdx.x & 63;
    int grp = lane >> 4;                          // 0..3
    int sub = lane & 15;                          // 0..15
    int node = blockIdx.x * 16 + wv * 4 + grp;    // grid exact: 3125*16 = 50000
    int j = row_ptr[node];
    int e = row_ptr[node + 1];

    float acc[8];
    #pragma unroll
    for (int k = 0; k < 8; ++k) acc[k] = 0.f;

    for (; j + 7 < e; j += 8) {
        Edge ed[8];
        #pragma unroll
        for (int u = 0; u < 8; ++u) ed[u] = edges[j + u];
        u16x8 v[8];
        #pragma unroll
        for (int u = 0; u < 8; ++u)
            v[u] = *(const u16x8*)(y + ((long long)ed[u].s << 7) + (sub << 3));
        #pragma unroll
        for (int u = 0; u < 8; ++u) {
            #pragma unroll
            for (int k = 0; k < 8; ++k)
                acc[k] = fmaf(ed[u].w, b2f(v[u][k]), acc[k]);
        }
    }
    for (; j + 3 < e; j += 4) {
        Edge ed[4];
        #pragma unroll
        for (int u = 0; u < 4; ++u) ed[u] = edges[j + u];
        u16x8 v[4];
        #pragma unroll
        for (int u = 0; u < 4; ++u)
            v[u] = *(const u16x8*)(y + ((long long)ed[u].s << 7) + (sub << 3));
        #pragma unroll
        for (int u = 0; u < 4; ++u) {
            #pragma unroll
            for (int k = 0; k < 8; ++k)
                acc[k] = fmaf(ed[u].w, b2f(v[u][k]), acc[k]);
        }
    }
    for (; j < e; ++j) {
        Edge ed0 = edges[j];
        u16x8 v0 = *(const u16x8*)(y + ((long long)ed0.s << 7) + (sub << 3));
        #pragma unroll
        for (int k = 0; k < 8; ++k)
            acc[k] = fmaf(ed0.w, b2f(v0[k]), acc[k]);
    }

    float4 bA = *(const float4*)(b1 + (sub << 3));
    float4 bB = *(const float4*)(b1 + (sub << 3) + 4);
    u16x8 hv;
    hv[0] = (unsigned short)f32_to_bf16_bits(fmaxf(acc[0] + bA.x, 0.f));
    hv[1] = (unsigned short)f32_to_bf16_bits(fmaxf(acc[1] + bA.y, 0.f));
    hv[2] = (unsigned short)f32_to_bf16_bits(fmaxf(acc[2] + bA.z, 0.f));
    hv[3] = (unsigned short)f32_to_bf16_bits(fmaxf(acc[3] + bA.w, 0.f));
    hv[4] = (unsigned short)f32_to_bf16_bits(fmaxf(acc[4] + bB.x, 0.f));
    hv[5] = (unsigned short)f32_to_bf16_bits(fmaxf(acc[5] + bB.y, 0.f));
    hv[6] = (unsigned short)f32_to_bf16_bits(fmaxf(acc[6] + bB.z, 0.f));
    hv[7] = (unsigned short)f32_to_bf16_bits(fmaxf(acc[7] + bB.w, 0.f));
    *(u16x8*)(h1 + ((long long)node << 7) + (sub << 3)) = hv;
}

// ---- 5) gemm2_mfma: g = h1 @ W2 via MFMA (mirrors gemm1's verified
// fragment/store layout). Replaces the LDS-read-bound scalar gemm2
// (~256M ds_read lane-ops) with a ~19MB streaming MFMA kernel.
// 3 n-tiles of 16 cover the 40 cols; cols 40..63 zero-padded ---------------
__global__ __launch_bounds__(256) void gemm2_mfma(const __hip_bfloat16* __restrict__ h1,
                                                  const float* __restrict__ W2,
                                                  __hip_bfloat16* __restrict__ g)
{
    __shared__ bf16x8 w2s[768];                   // 12 KB: 4 ks x 3 nt x 64 lanes
    int t = threadIdx.x;
    for (int f = t; f < 768; f += 256) {          // 3 frags per thread
        int lane = f & 63;
        int nt = (f >> 6) % 3;
        int ks = f / 192;
        int m = lane & 15, quad = lane >> 4;
        int col = nt * 16 + m;
        bf16x8 frag;
        #pragma unroll
        for (int j = 0; j < 8; ++j) {
            int k = ks * 32 + quad * 8 + j;
            float val = (col < OUT_DIM) ? W2[k * OUT_DIM + col] : 0.f;
            frag[j] = (short)f32_to_bf16_bits(val);
        }
        w2s[f] = frag;
    }
    __syncthreads();

    int wv = t >> 6;
    int lane = t & 63;
    int m = lane & 15, quad = lane >> 4;
    int row0 = blockIdx.x * 64 + wv * 16;
    int arow = row0 + m;
    if (arow >= N_NODES) arow = N_NODES - 1;      // clamp loads; stores guarded

    bf16x8 afrag[4];
    #pragma unroll
    for (int ks = 0; ks < 4; ++ks)
        afrag[ks] = *(const bf16x8*)(h1 + (long long)arow * HIDDEN + ks * 32 + quad * 8);

    f32x4 acc[3];
    #pragma unroll
    for (int nt = 0; nt < 3; ++nt) acc[nt] = (f32x4){0.f, 0.f, 0.f, 0.f};

    #pragma unroll
    for (int ks = 0; ks < 4; ++ks) {
        #pragma unroll
        for (int nt = 0; nt < 3; ++nt) {
            bf16x8 bfrag = w2s[(ks * 3 + nt) * 64 + lane];
            acc[nt] = __builtin_amdgcn_mfma_f32_16x16x32_bf16(afrag[ks], bfrag, acc[nt], 0, 0, 0);
        }
    }

    #pragma unroll
    for (int nt = 0; nt < 3; ++nt) {
        int col = nt * 16 + m;
        if (col < OUT_DIM) {
            #pragma unroll
            for (int r = 0; r < 4; ++r) {
                int rrow = row0 + quad * 4 + r;
                if (rrow < N_NODES)
                    g[(rrow << 6) + col] = __float2bfloat16(acc[nt][r]);
            }
        }
    }
    // zero pad cols 40..63 (each lane with m<6 zeroes one u16x4 per row)
    if (m < 6) {
        u16x4 z = (u16x4){0, 0, 0, 0};
        #pragma unroll
        for (int r = 0; r < 4; ++r) {
            int rrow = row0 + quad * 4 + r;
            if (rrow < N_NODES)
                *(u16x4*)(g + (rrow << 6) + OUT_DIM + m * 4) = z;
        }
    }
}

// ---- 6) spmm2: out = A @ g + b2. 16-lane groups, 8B/lane = one 128B line -
__global__ __launch_bounds__(256) void spmm2_kernel(const int* __restrict__ row_ptr,
                                                    const Edge* __restrict__ edges,
                                                    const __hip_bfloat16* __restrict__ g,
                                                    const float* __restrict__ b2,
                                                    float* __restrict__ out)
{
    int wv = threadIdx.x >> 6;
    int lane = threadIdx.x & 63;
    int grp = lane >> 4;                          // 0..3
    int sub = lane & 15;                          // 0..15
    int node = blockIdx.x * 16 + wv * 4 + grp;    // grid exact: 3125*16 = 50000
    int j = row_ptr[node];
    int e = row_ptr[node + 1];

    float acc[4];
    #pragma unroll
    for (int k = 0; k < 4; ++k) acc[k] = 0.f;

    for (; j + 7 < e; j += 8) {
        Edge ed[8];
        #pragma unroll
        for (int u = 0; u < 8; ++u) ed[u] = edges[j + u];
        u16x4 v[8];
        #pragma unroll
        for (int u = 0; u < 8; ++u)
            v[u] = *(const u16x4*)(g + ((long long)ed[u].s << 6) + (sub << 2));
        #pragma unroll
        for (int u = 0; u < 8; ++u) {
            #pragma unroll
            for (int k = 0; k < 4; ++k)
                acc[k] = fmaf(ed[u].w, b2f(v[u][k]), acc[k]);
        }
    }
    for (; j + 3 < e; j += 4) {
        Edge ed[4];
        #pragma unroll
        for (int u = 0; u < 4; ++u) ed[u] = edges[j + u];
        u16x4 v[4];
        #pragma unroll
        for (int u = 0; u < 4; ++u)
            v[u] = *(const u16x4*)(g + ((long long)ed[u].s << 6) + (sub << 2));
        #pragma unroll
        for (int u = 0; u < 4; ++u) {
            #pragma unroll
            for (int k = 0; k < 4; ++k)
                acc[k] = fmaf(ed[u].w, b2f(v[u][k]), acc[k]);
        }
    }
    for (; j < e; ++j) {
        Edge ed0 = edges[j];
        u16x4 v0 = *(const u16x4*)(g + ((long long)ed0.s << 6) + (sub << 2));
        #pragma unroll
        for (int k = 0; k < 4; ++k)
            acc[k] = fmaf(ed0.w, b2f(v0[k]), acc[k]);
    }

    if (sub < 10) {                               // cols 4*sub..4*sub+3 < 40
        float4 bb = *(const float4*)(b2 + (sub << 2));
        float4 o;
        o.x = acc[0] + bb.x;
        o.y = acc[1] + bb.y;
        o.z = acc[2] + bb.z;
        o.w = acc[3] + bb.w;
        *(float4*)(out + (long long)node * OUT_DIM + (sub << 2)) = o;
    }
}

extern "C" void kernel_launch(void* const* d_in, const int* in_sizes, int n_in,
                              void* d_out, int out_size, void* d_ws, size_t ws_size,
                              hipStream_t stream)
{
    const float* x    = (const float*)d_in[0];
    const int*   esrc = (const int*)  d_in[1];
    const int*   edst = (const int*)  d_in[2];
    const float* ew   = (const float*)d_in[3];
    const float* W1   = (const float*)d_in[4];
    const float* b1   = (const float*)d_in[5];
    const float* W2   = (const float*)d_in[6];
    const float* b2   = (const float*)d_in[7];
    float* out = (float*)d_out;

    // workspace layout (~36 MB); g aliases y (y is dead after spmm1)
    __hip_bfloat16* y  = (__hip_bfloat16*)d_ws;                  // 12.8 MB
    __hip_bfloat16* g  = y;                                      // 6.4 MB (aliased)
    __hip_bfloat16* h1 = y + (size_t)N_NODES * HIDDEN;           // 12.8 MB
    Edge* edges     = (Edge*)(h1 + (size_t)N_NODES * HIDDEN);    // 6.4 MB
    int* hist8      = (int*)(edges + N_EDGES);                   // 1.6 MB (8 copies; [50000..50048] of copy 0 = scan flags)
    unsigned short* erank = (unsigned short*)(hist8 + N_COPIES * HIST_STRIDE); // 1.6 MB
    int* row_ptr    = (int*)(erank + N_EDGES);                   // 50001 (pad 50176)

    // CSR build + gemm1 co-run (interleaved 1:4 so MFMA overlaps atomics)
    hipMemsetAsync(hist8, 0, N_COPIES * HIST_STRIDE * sizeof(int), stream);
    hist_gemm1<<<HG_GRID, 256, 0, stream>>>(edst, esrc, hist8, erank, x, W1, y);
    scan_fused<<<SCAN_BLOCKS, SCAN_BS, 0, stream>>>(hist8, row_ptr);
    scatter_det<<<N_EDGES / 256, 256, 0, stream>>>(esrc, edst, ew, hist8,
                                                   erank, row_ptr, edges);

    // h1 = relu(A @ y + b1)
    spmm1_kernel<<<N_NODES / 16, 256, 0, stream>>>(row_ptr, edges, y, b1, h1);
    // g = h1 @ W2 (MFMA; padded+zero-filled g rows)
    gemm2_mfma<<<G1_BLOCKS, 256, 0, stream>>>(h1, W2, g);
    // out = A @ g + b2
    spmm2_kernel<<<N_NODES / 16, 256, 0, stream>>>(row_ptr, edges, g, b2, out);
}

// Round 10
// 180.669 us; speedup vs baseline: 1.1987x; 1.1186x over previous
//
#include <hip/hip_runtime.h>
#include <hip/hip_bf16.h>

#define N_NODES 50000
#define N_EDGES 800000
#define IN_DIM 128
#define HIDDEN 128
#define OUT_DIM 40
#define G_STRIDE 64                                       // padded g row (128B line)

#define SCAN_BS 1024
#define SCAN_BLOCKS ((N_NODES + SCAN_BS - 1) / SCAN_BS)   // 49

#define CHUNK_SHIFT 13
#define CHUNK 8192
#define NCHUNK 98                                         // 98*8192 = 802816 >= 800000
#define CNT_STRIDE 50176                                  // u8 per chunk, line-aligned
#define CNT_WORDS (CNT_STRIDE / 4)                        // 12544 u32 words (49 KB)

#define G1_ROWS 128                                       // rows per gemm1 block (512 thr)
#define G1_BLOCKS ((N_NODES + G1_ROWS - 1) / G1_ROWS)     // 391
#define HG_GRID (NCHUNK + G1_BLOCKS)                      // 489

struct __align__(8) Edge { int s; float w; };

typedef __attribute__((ext_vector_type(8))) short bf16x8;   // MFMA A/B frag (4 VGPR)
typedef __attribute__((ext_vector_type(4))) float f32x4;    // MFMA C/D frag
typedef __attribute__((ext_vector_type(8))) unsigned short u16x8;
typedef __attribute__((ext_vector_type(4))) unsigned short u16x4;

// fp32 -> bf16 bits with round-to-nearest-even
__device__ __forceinline__ unsigned f32_to_bf16_bits(float f) {
    unsigned u = __float_as_uint(f);
    return (u + 0x7FFFu + ((u >> 16) & 1u)) >> 16;
}
// bf16 bits -> fp32
__device__ __forceinline__ float b2f(unsigned short u) {
    return __uint_as_float(((unsigned)u) << 16);
}

// ---- 1) fused histA + gemm1, 512 threads/block.
// Blocks 0..97: per-chunk LDS histogram (byte-packed counters, 49 KB) via
// LDS atomicAdd -> rank byte per edge; dump counters coalesced to cnt[].
// Replaces the 800K global returning atomics (measured 44us floor) with
// bank-rate LDS atomics. Blocks 98..488: gemm1 MFMA (128 rows each),
// backfilling the CUs phase A doesn't occupy.
__global__ __launch_bounds__(512) void hist_gemm1(const int* __restrict__ dst,
                                                  unsigned char* __restrict__ cnt,
                                                  unsigned char* __restrict__ erank,
                                                  const float* __restrict__ x,
                                                  const float* __restrict__ W1,
                                                  __hip_bfloat16* __restrict__ y)
{
    __shared__ __align__(16) unsigned int shmem[CNT_WORDS];   // 49 KB union
    int bid = blockIdx.x;
    int t = threadIdx.x;

    if (bid < NCHUNK) {
        // -------- phase A: LDS ranked histogram for chunk bid --------
        for (int f = t; f < CNT_WORDS; f += 512) shmem[f] = 0u;
        __syncthreads();
        int base = bid << CHUNK_SHIFT;
        #pragma unroll
        for (int r = 0; r < CHUNK / 512; ++r) {
            int i = base + r * 512 + t;
            if (i < N_EDGES) {
                int d = dst[i];
                unsigned sh = (unsigned)(d & 3) * 8u;
                unsigned old = atomicAdd(&shmem[d >> 2], 1u << sh);
                erank[i] = (unsigned char)((old >> sh) & 0xffu);
            }
        }
        __syncthreads();
        unsigned int* cw = (unsigned int*)(cnt + (size_t)bid * CNT_STRIDE);
        for (int f = t; f < CNT_WORDS; f += 512) cw[f] = shmem[f];
        return;
    }

    // -------- gemm1 path: y = x @ W1 (v_mfma_f32_16x16x32_bf16) --------
    bf16x8* w1s = (bf16x8*)shmem;                 // 32 KB of the union
    int gb = bid - NCHUNK;                        // 0..390
    for (int f = t; f < 2048; f += 512) {         // 4 frags per thread
        int lane = f & 63;
        int nt = (f >> 6) & 7;
        int ks = f >> 9;
        int m = lane & 15, quad = lane >> 4;
        bf16x8 frag;
        #pragma unroll
        for (int j = 0; j < 8; ++j) {
            int k = ks * 32 + quad * 8 + j;
            frag[j] = (short)f32_to_bf16_bits(W1[k * HIDDEN + nt * 16 + m]);
        }
        w1s[f] = frag;
    }
    __syncthreads();

    int wv = t >> 6;                              // 0..7
    int lane = t & 63;
    int m = lane & 15, quad = lane >> 4;
    int row0 = gb * G1_ROWS + wv * 16;
    int arow = row0 + m;
    if (arow >= N_NODES) arow = N_NODES - 1;      // clamp loads; stores guarded

    bf16x8 afrag[4];
    #pragma unroll
    for (int ks = 0; ks < 4; ++ks) {
        const float4* xp = (const float4*)(x + (long long)arow * IN_DIM + ks * 32 + quad * 8);
        float4 a0 = xp[0], a1 = xp[1];
        afrag[ks][0] = (short)f32_to_bf16_bits(a0.x);
        afrag[ks][1] = (short)f32_to_bf16_bits(a0.y);
        afrag[ks][2] = (short)f32_to_bf16_bits(a0.z);
        afrag[ks][3] = (short)f32_to_bf16_bits(a0.w);
        afrag[ks][4] = (short)f32_to_bf16_bits(a1.x);
        afrag[ks][5] = (short)f32_to_bf16_bits(a1.y);
        afrag[ks][6] = (short)f32_to_bf16_bits(a1.z);
        afrag[ks][7] = (short)f32_to_bf16_bits(a1.w);
    }

    f32x4 acc[8];
    #pragma unroll
    for (int nt = 0; nt < 8; ++nt) acc[nt] = (f32x4){0.f, 0.f, 0.f, 0.f};

    #pragma unroll
    for (int ks = 0; ks < 4; ++ks) {
        #pragma unroll
        for (int nt = 0; nt < 8; ++nt) {
            bf16x8 bfrag = w1s[(ks * 8 + nt) * 64 + lane];
            acc[nt] = __builtin_amdgcn_mfma_f32_16x16x32_bf16(afrag[ks], bfrag, acc[nt], 0, 0, 0);
        }
    }

    #pragma unroll
    for (int nt = 0; nt < 8; ++nt) {
        #pragma unroll
        for (int r = 0; r < 4; ++r) {
            int rrow = row0 + quad * 4 + r;
            if (rrow < N_NODES)
                y[(long long)rrow * HIDDEN + nt * 16 + m] = __float2bfloat16(acc[nt][r]);
        }
    }
}

// ---- 2) scan_fused: per-chunk u8 counters -> exclusive offsets (in place),
// block totals, cross-block prefix via release/acquire spin (49 co-resident
// blocks; block b spins only on blocks < b: acyclic), block-local scan -----
__global__ __launch_bounds__(SCAN_BS) void scan_fused(unsigned char* __restrict__ cnt,
                                                      int* __restrict__ row_ptr,
                                                      int* __restrict__ flags)
{
    __shared__ int tmp[SCAN_BS];
    __shared__ int red[SCAN_BS / 64];
    __shared__ int blk_off;
    int t = threadIdx.x;
    int bid = blockIdx.x;
    int i = bid * SCAN_BS + t;

    int total = 0;
    if (i < N_NODES) {
        int off = 0;
        for (int c = 0; c < NCHUNK; ++c) {
            unsigned char h = cnt[(size_t)c * CNT_STRIDE + i];
            cnt[(size_t)c * CNT_STRIDE + i] = (unsigned char)off;  // excl prefix
            off += h;
        }
        total = off;                               // = degree(i), <= ~60
    }
    // block total
    int s = total;
    for (int off = 32; off > 0; off >>= 1) s += __shfl_down(s, off, 64);
    int wave = t >> 6, lane = t & 63;
    if (lane == 0) red[wave] = s;
    __syncthreads();
    if (t == 0) {
        int tt = 0;
        #pragma unroll
        for (int wv = 0; wv < SCAN_BS / 64; ++wv) tt += red[wv];
        __hip_atomic_store(&flags[bid], tt + 1,
                           __ATOMIC_RELEASE, __HIP_MEMORY_SCOPE_AGENT);
    }
    // cross-block exclusive prefix
    if (t < 64) {
        int v2 = 0;
        if (t < bid) {
            int v;
            do {
                v = __hip_atomic_load(&flags[t],
                                      __ATOMIC_ACQUIRE, __HIP_MEMORY_SCOPE_AGENT);
            } while (v == 0);
            v2 = v - 1;
        }
        for (int off = 32; off > 0; off >>= 1) v2 += __shfl_down(v2, off, 64);
        if (t == 0) {
            blk_off = v2;
            if (bid == 0) row_ptr[N_NODES] = N_EDGES;
        }
    }
    // block-local exclusive scan
    int v = total;
    tmp[t] = v;
    __syncthreads();
    for (int off = 1; off < SCAN_BS; off <<= 1) {
        int u = (t >= off) ? tmp[t - off] : 0;
        __syncthreads();
        tmp[t] += u;
        __syncthreads();
    }
    if (i < N_NODES) row_ptr[i] = tmp[t] - v + blk_off;
}

// ---- 3) scatter_det: single-pass placement, no atomics.
// pos = row_ptr[d] + cnt[chunk][d] + erank[i]; chunk's 50KB cnt window is
// L2-resident for the block's contiguous edge range ------------------------
__global__ __launch_bounds__(256) void scatter_det(const int* __restrict__ src,
                                                   const int* __restrict__ dst,
                                                   const float* __restrict__ w,
                                                   const unsigned char* __restrict__ cnt,
                                                   const unsigned char* __restrict__ erank,
                                                   const int* __restrict__ row_ptr,
                                                   Edge* __restrict__ edges)
{
    int i = blockIdx.x * 256 + threadIdx.x;       // grid exact: 3125*256
    int d = dst[i];
    int chunk = i >> CHUNK_SHIFT;
    int pos = row_ptr[d] + (int)cnt[(size_t)chunk * CNT_STRIDE + d] + (int)erank[i];
    Edge ed; ed.s = src[i]; ed.w = w[i];
    edges[pos] = ed;
}

// ---- 4) spmm1: h1 = relu(A @ y + b1). 16-lane groups, 16B/lane, 4 nodes
// per wave, 8-deep gather chains -------------------------------------------
__global__ __launch_bounds__(256) void spmm1_kernel(const int* __restrict__ row_ptr,
                                                    const Edge* __restrict__ edges,
                                                    const __hip_bfloat16* __restrict__ y,
                                                    const float* __restrict__ b1,
                                                    __hip_bfloat16* __restrict__ h1)
{
    int wv = threadIdx.x >> 6;
    int lane = threadIdx.x & 63;
    int grp = lane >> 4;                          // 0..3
    int sub = lane & 15;                          // 0..15
    int node = blockIdx.x * 16 + wv * 4 + grp;    // grid exact: 3125*16 = 50000
    int j = row_ptr[node];
    int e = row_ptr[node + 1];

    float acc[8];
    #pragma unroll
    for (int k = 0; k < 8; ++k) acc[k] = 0.f;

    for (; j + 7 < e; j += 8) {
        Edge ed[8];
        #pragma unroll
        for (int u = 0; u < 8; ++u) ed[u] = edges[j + u];
        u16x8 v[8];
        #pragma unroll
        for (int u = 0; u < 8; ++u)
            v[u] = *(const u16x8*)(y + ((long long)ed[u].s << 7) + (sub << 3));
        #pragma unroll
        for (int u = 0; u < 8; ++u) {
            #pragma unroll
            for (int k = 0; k < 8; ++k)
                acc[k] = fmaf(ed[u].w, b2f(v[u][k]), acc[k]);
        }
    }
    for (; j + 3 < e; j += 4) {
        Edge ed[4];
        #pragma unroll
        for (int u = 0; u < 4; ++u) ed[u] = edges[j + u];
        u16x8 v[4];
        #pragma unroll
        for (int u = 0; u < 4; ++u)
            v[u] = *(const u16x8*)(y + ((long long)ed[u].s << 7) + (sub << 3));
        #pragma unroll
        for (int u = 0; u < 4; ++u) {
            #pragma unroll
            for (int k = 0; k < 8; ++k)
                acc[k] = fmaf(ed[u].w, b2f(v[u][k]), acc[k]);
        }
    }
    for (; j < e; ++j) {
        Edge ed0 = edges[j];
        u16x8 v0 = *(const u16x8*)(y + ((long long)ed0.s << 7) + (sub << 3));
        #pragma unroll
        for (int k = 0; k < 8; ++k)
            acc[k] = fmaf(ed0.w, b2f(v0[k]), acc[k]);
    }

    float4 bA = *(const float4*)(b1 + (sub << 3));
    float4 bB = *(const float4*)(b1 + (sub << 3) + 4);
    u16x8 hv;
    hv[0] = (unsigned short)f32_to_bf16_bits(fmaxf(acc[0] + bA.x, 0.f));
    hv[1] = (unsigned short)f32_to_bf16_bits(fmaxf(acc[1] + bA.y, 0.f));
    hv[2] = (unsigned short)f32_to_bf16_bits(fmaxf(acc[2] + bA.z, 0.f));
    hv[3] = (unsigned short)f32_to_bf16_bits(fmaxf(acc[3] + bA.w, 0.f));
    hv[4] = (unsigned short)f32_to_bf16_bits(fmaxf(acc[4] + bB.x, 0.f));
    hv[5] = (unsigned short)f32_to_bf16_bits(fmaxf(acc[5] + bB.y, 0.f));
    hv[6] = (unsigned short)f32_to_bf16_bits(fmaxf(acc[6] + bB.z, 0.f));
    hv[7] = (unsigned short)f32_to_bf16_bits(fmaxf(acc[7] + bB.w, 0.f));
    *(u16x8*)(h1 + ((long long)node << 7) + (sub << 3)) = hv;
}

// ---- 5) gemm2_mfma: g = h1 @ W2 via MFMA; 3 n-tiles cover 40 cols,
// cols 40..63 zero-padded ---------------------------------------------------
__global__ __launch_bounds__(256) void gemm2_mfma(const __hip_bfloat16* __restrict__ h1,
                                                  const float* __restrict__ W2,
                                                  __hip_bfloat16* __restrict__ g)
{
    __shared__ bf16x8 w2s[768];                   // 12 KB: 4 ks x 3 nt x 64 lanes
    int t = threadIdx.x;
    for (int f = t; f < 768; f += 256) {          // 3 frags per thread
        int lane = f & 63;
        int nt = (f >> 6) % 3;
        int ks = f / 192;
        int m = lane & 15, quad = lane >> 4;
        int col = nt * 16 + m;
        bf16x8 frag;
        #pragma unroll
        for (int j = 0; j < 8; ++j) {
            int k = ks * 32 + quad * 8 + j;
            float val = (col < OUT_DIM) ? W2[k * OUT_DIM + col] : 0.f;
            frag[j] = (short)f32_to_bf16_bits(val);
        }
        w2s[f] = frag;
    }
    __syncthreads();

    int wv = t >> 6;
    int lane = t & 63;
    int m = lane & 15, quad = lane >> 4;
    int row0 = blockIdx.x * 64 + wv * 16;
    int arow = row0 + m;
    if (arow >= N_NODES) arow = N_NODES - 1;      // clamp loads; stores guarded

    bf16x8 afrag[4];
    #pragma unroll
    for (int ks = 0; ks < 4; ++ks)
        afrag[ks] = *(const bf16x8*)(h1 + (long long)arow * HIDDEN + ks * 32 + quad * 8);

    f32x4 acc[3];
    #pragma unroll
    for (int nt = 0; nt < 3; ++nt) acc[nt] = (f32x4){0.f, 0.f, 0.f, 0.f};

    #pragma unroll
    for (int ks = 0; ks < 4; ++ks) {
        #pragma unroll
        for (int nt = 0; nt < 3; ++nt) {
            bf16x8 bfrag = w2s[(ks * 3 + nt) * 64 + lane];
            acc[nt] = __builtin_amdgcn_mfma_f32_16x16x32_bf16(afrag[ks], bfrag, acc[nt], 0, 0, 0);
        }
    }

    #pragma unroll
    for (int nt = 0; nt < 3; ++nt) {
        int col = nt * 16 + m;
        if (col < OUT_DIM) {
            #pragma unroll
            for (int r = 0; r < 4; ++r) {
                int rrow = row0 + quad * 4 + r;
                if (rrow < N_NODES)
                    g[(rrow << 6) + col] = __float2bfloat16(acc[nt][r]);
            }
        }
    }
    // zero pad cols 40..63
    if (m < 6) {
        u16x4 z = (u16x4){0, 0, 0, 0};
        #pragma unroll
        for (int r = 0; r < 4; ++r) {
            int rrow = row0 + quad * 4 + r;
            if (rrow < N_NODES)
                *(u16x4*)(g + (rrow << 6) + OUT_DIM + m * 4) = z;
        }
    }
}

// ---- 6) spmm2: out = A @ g + b2. 16-lane groups, 8B/lane = one 128B line -
__global__ __launch_bounds__(256) void spmm2_kernel(const int* __restrict__ row_ptr,
                                                    const Edge* __restrict__ edges,
                                                    const __hip_bfloat16* __restrict__ g,
                                                    const float* __restrict__ b2,
                                                    float* __restrict__ out)
{
    int wv = threadIdx.x >> 6;
    int lane = threadIdx.x & 63;
    int grp = lane >> 4;                          // 0..3
    int sub = lane & 15;                          // 0..15
    int node = blockIdx.x * 16 + wv * 4 + grp;    // grid exact: 3125*16 = 50000
    int j = row_ptr[node];
    int e = row_ptr[node + 1];

    float acc[4];
    #pragma unroll
    for (int k = 0; k < 4; ++k) acc[k] = 0.f;

    for (; j + 7 < e; j += 8) {
        Edge ed[8];
        #pragma unroll
        for (int u = 0; u < 8; ++u) ed[u] = edges[j + u];
        u16x4 v[8];
        #pragma unroll
        for (int u = 0; u < 8; ++u)
            v[u] = *(const u16x4*)(g + ((long long)ed[u].s << 6) + (sub << 2));
        #pragma unroll
        for (int u = 0; u < 8; ++u) {
            #pragma unroll
            for (int k = 0; k < 4; ++k)
                acc[k] = fmaf(ed[u].w, b2f(v[u][k]), acc[k]);
        }
    }
    for (; j + 3 < e; j += 4) {
        Edge ed[4];
        #pragma unroll
        for (int u = 0; u < 4; ++u) ed[u] = edges[j + u];
        u16x4 v[4];
        #pragma unroll
        for (int u = 0; u < 4; ++u)
            v[u] = *(const u16x4*)(g + ((long long)ed[u].s << 6) + (sub << 2));
        #pragma unroll
        for (int u = 0; u < 4; ++u) {
            #pragma unroll
            for (int k = 0; k < 4; ++k)
                acc[k] = fmaf(ed[u].w, b2f(v[u][k]), acc[k]);
        }
    }
    for (; j < e; ++j) {
        Edge ed0 = edges[j];
        u16x4 v0 = *(const u16x4*)(g + ((long long)ed0.s << 6) + (sub << 2));
        #pragma unroll
        for (int k = 0; k < 4; ++k)
            acc[k] = fmaf(ed0.w, b2f(v0[k]), acc[k]);
    }

    if (sub < 10) {                               // cols 4*sub..4*sub+3 < 40
        float4 bb = *(const float4*)(b2 + (sub << 2));
        float4 o;
        o.x = acc[0] + bb.x;
        o.y = acc[1] + bb.y;
        o.z = acc[2] + bb.z;
        o.w = acc[3] + bb.w;
        *(float4*)(out + (long long)node * OUT_DIM + (sub << 2)) = o;
    }
}

extern "C" void kernel_launch(void* const* d_in, const int* in_sizes, int n_in,
                              void* d_out, int out_size, void* d_ws, size_t ws_size,
                              hipStream_t stream)
{
    const float* x    = (const float*)d_in[0];
    const int*   esrc = (const int*)  d_in[1];
    const int*   edst = (const int*)  d_in[2];
    const float* ew   = (const float*)d_in[3];
    const float* W1   = (const float*)d_in[4];
    const float* b1   = (const float*)d_in[5];
    const float* W2   = (const float*)d_in[6];
    const float* b2   = (const float*)d_in[7];
    float* out = (float*)d_out;

    // workspace layout (~38 MB); g aliases y (y is dead after spmm1)
    __hip_bfloat16* y  = (__hip_bfloat16*)d_ws;                  // 12.8 MB
    __hip_bfloat16* g  = y;                                      // 6.4 MB (aliased)
    __hip_bfloat16* h1 = y + (size_t)N_NODES * HIDDEN;           // 12.8 MB
    Edge* edges     = (Edge*)(h1 + (size_t)N_NODES * HIDDEN);    // 6.4 MB
    unsigned char* cnt   = (unsigned char*)(edges + N_EDGES);    // 4.9 MB (98 chunks u8)
    unsigned char* erank = cnt + (size_t)NCHUNK * CNT_STRIDE;    // 0.8 MB
    int* row_ptr    = (int*)(erank + N_EDGES);                   // 50001 (pad 50176)
    int* flags      = row_ptr + 50176;                           // 64 ints (scan sync)

    // scan-flag reset (tiny); cnt needs no memset (phase A fully overwrites)
    hipMemsetAsync(flags, 0, 64 * sizeof(int), stream);
    // CSR phase A (LDS ranked histograms) + gemm1 co-run, one dispatch
    hist_gemm1<<<HG_GRID, 512, 0, stream>>>(edst, cnt, erank, x, W1, y);
    // offsets + row_ptr in one kernel (spin-synced cross-block prefix)
    scan_fused<<<SCAN_BLOCKS, SCAN_BS, 0, stream>>>(cnt, row_ptr, flags);
    // deterministic scatter
    scatter_det<<<N_EDGES / 256, 256, 0, stream>>>(esrc, edst, ew, cnt,
                                                   erank, row_ptr, edges);

    // h1 = relu(A @ y + b1)
    spmm1_kernel<<<N_NODES / 16, 256, 0, stream>>>(row_ptr, edges, y, b1, h1);
    // g = h1 @ W2 (MFMA; padded+zero-filled g rows)
    gemm2_mfma<<<(N_NODES + 63) / 64, 256, 0, stream>>>(h1, W2, g);
    // out = A @ g + b2
    spmm2_kernel<<<N_NODES / 16, 256, 0, stream>>>(row_ptr, edges, g, b2, out);
}